// Round 18
// baseline (189.764 us; speedup 1.0000x reference)
//
#include <hip/hip_runtime.h>
#include <cstddef>

// Problem constants (match reference)
constexpr int NN = 20000;    // nodes
constexpr int NE = 320000;   // edges
constexpr int NQ = 100000;   // queries
constexpr int DD = 256;      // feature dim
constexpr int NB = (NN + 255) / 256;       // scan blocks (79)
constexpr int DEGB = (NE + 255) / 256;     // deg/fill blocks (1250)
constexpr int CASTB = (NN * DD / 8 + 255) / 256;   // 2500 cast blocks

typedef __attribute__((ext_vector_type(8))) short bf16x8;
typedef __attribute__((ext_vector_type(4))) float f32x4;
typedef __attribute__((ext_vector_type(4))) unsigned short u16x4;
typedef __attribute__((ext_vector_type(8))) unsigned short u16x8;

__device__ inline unsigned short f2bf(float f) {
    union { float f; unsigned u; } v; v.f = f;
    unsigned r = v.u + 0x7fffu + ((v.u >> 16) & 1u);   // RNE
    return (unsigned short)(r >> 16);
}
__device__ inline float bf2f(unsigned short h) {
    union { unsigned u; float f; } t; t.u = ((unsigned)h) << 16;
    return t.f;
}

// ---------------------------------------------------------------------------
// Fused: blocks [0,CASTB): emb f32->bf16 + deg zero (+ block 0: bflag zero).
//        blocks [CASTB, CASTB+160): pack 5 weight matrices into bf16 MFMA
//        B-fragment layout, HI ONLY (absmax 0.0078 vs threshold 0.0176).
__global__ __launch_bounds__(256) void k_castpack(
    const float* __restrict__ x, unsigned short* __restrict__ y,
    int* __restrict__ deg, int* __restrict__ bflag,
    const float* __restrict__ w0, const float* __restrict__ w1,
    const float* __restrict__ w2, const float* __restrict__ w3,
    const float* __restrict__ w4,
    unsigned short* __restrict__ h0, unsigned short* __restrict__ h1,
    unsigned short* __restrict__ h2, unsigned short* __restrict__ h3,
    unsigned short* __restrict__ h4) {
    const int bid = blockIdx.x;
    if (bid < CASTB) {
        int i = bid * 256 + threadIdx.x;   // 8 elems per thread
        if (i < NN) deg[i] = 0;
        if (bid == 0 && threadIdx.x < NB) bflag[threadIdx.x] = 0;
        if (i >= NN * DD / 8) return;
        float4 f0 = *reinterpret_cast<const float4*>(x + (size_t)i * 8);
        float4 f1 = *reinterpret_cast<const float4*>(x + (size_t)i * 8 + 4);
        u16x8 o;
        o[0] = f2bf(f0.x); o[1] = f2bf(f0.y); o[2] = f2bf(f0.z); o[3] = f2bf(f0.w);
        o[4] = f2bf(f1.x); o[5] = f2bf(f1.y); o[6] = f2bf(f1.z); o[7] = f2bf(f1.w);
        *reinterpret_cast<u16x8*>(y + (size_t)i * 8) = o;
        return;
    }
    int mb = bid - CASTB;                   // 0..159
    int m = mb >> 5;
    int idx = (mb & 31) * 256 + threadIdx.x;   // 0..8191
    const float* W = (m == 0) ? w0 : (m == 1) ? w1 : (m == 2) ? w2 : (m == 3) ? w3 : w4;
    unsigned short* H = (m == 0) ? h0 : (m == 1) ? h1 : (m == 2) ? h2 : (m == 3) ? h3 : h4;
    int t = idx >> 6, lane = idx & 63;
    int kt = t >> 4, nt = t & 15;
    int k0 = kt * 32 + (lane >> 4) * 8;
    int n = nt * 16 + (lane & 15);
    unsigned uh[4];
#pragma unroll
    for (int i = 0; i < 4; ++i) {
        unsigned lo = f2bf(W[(size_t)(k0 + 2 * i) * DD + n]);
        unsigned hi = f2bf(W[(size_t)(k0 + 2 * i + 1) * DD + n]);
        uh[i] = lo | (hi << 16);
    }
    *reinterpret_cast<uint4*>(H + (size_t)idx * 8) = make_uint4(uh[0], uh[1], uh[2], uh[3]);
}

// ---------------------------------------------------------------------------
// Dense dual GEMM body: P = A @ Wl, Q = A @ Wr (all bf16, hi-only weights).
// R18 retile: wave = ONE 16-row M-tile x 32 cols -> 2504 blocks (2x waves of
// R17). R15 proved lin is LATENCY-bound (halving work was neutral), so the
// lever is wave count, not per-wave efficiency. acc = 16 VGPR.
__device__ __forceinline__ void lin_body(
    int bidx,
    const unsigned short* __restrict__ A,
    const unsigned short* __restrict__ Wl, const unsigned short* __restrict__ Wr,
    unsigned short* __restrict__ P, unsigned short* __restrict__ Q) {
    const int ns   = bidx & 7;
    const int mblk = bidx >> 3;
    const int wave = threadIdx.x >> 6;
    const int lane = threadIdx.x & 63;
    const int row0 = mblk * 64 + wave * 16;
    const int kcol = (lane >> 4) * 8;
    const int ar = min(row0 + (lane & 15), NN - 1);

    f32x4 accP[2], accQ[2];
#pragma unroll
    for (int nt = 0; nt < 2; ++nt) {
        accP[nt] = {0, 0, 0, 0};
        accQ[nt] = {0, 0, 0, 0};
    }

#pragma unroll 4
    for (int kt = 0; kt < 8; ++kt) {
        bf16x8 a = *reinterpret_cast<const bf16x8*>(A + (size_t)ar * DD + kt * 32 + kcol);
#pragma unroll
        for (int nt = 0; nt < 2; ++nt) {
            const size_t fo = ((size_t)((kt * 16 + ns * 2 + nt) * 64 + lane)) * 8;
            bf16x8 bl = *reinterpret_cast<const bf16x8*>(Wl + fo);
            bf16x8 br = *reinterpret_cast<const bf16x8*>(Wr + fo);
            __builtin_amdgcn_s_setprio(1);
            accP[nt] = __builtin_amdgcn_mfma_f32_16x16x32_bf16(a, bl, accP[nt], 0, 0, 0);
            accQ[nt] = __builtin_amdgcn_mfma_f32_16x16x32_bf16(a, br, accQ[nt], 0, 0, 0);
            __builtin_amdgcn_s_setprio(0);
        }
    }

    const int n0 = lane & 15;
    const int rg = (lane >> 4) * 4;
#pragma unroll
    for (int nt = 0; nt < 2; ++nt) {
        int n = (ns * 2 + nt) * 16 + n0;
#pragma unroll
        for (int j = 0; j < 4; ++j) {
            int r = row0 + rg + j;
            if (r < NN) {
                P[(size_t)r * DD + n] = f2bf(accP[nt][j]);
                Q[(size_t)r * DD + n] = f2bf(accQ[nt][j]);
            }
        }
    }
}

// Layer-2 standalone GEMM.
__global__ __launch_bounds__(256) void k_lin(
    const unsigned short* __restrict__ A,
    const unsigned short* __restrict__ Wl, const unsigned short* __restrict__ Wr,
    unsigned short* __restrict__ P, unsigned short* __restrict__ Q) {
    lin_body(blockIdx.x, A, Wl, Wr, P, Q);
}

// Fused: blocks [0,DEGB) = degree histogram; rest = layer-1 GEMM.
__global__ __launch_bounds__(256) void k_deglin(
    const int* __restrict__ row, int* __restrict__ deg,
    const unsigned short* __restrict__ A,
    const unsigned short* __restrict__ Wl, const unsigned short* __restrict__ Wr,
    unsigned short* __restrict__ P, unsigned short* __restrict__ Q) {
    if (blockIdx.x < DEGB) {
        int e = blockIdx.x * 256 + threadIdx.x;
        if (e < NE) atomicAdd(&deg[row[e]], 1);
        return;
    }
    lin_body(blockIdx.x - DEGB, A, Wl, Wr, P, Q);
}

// ---------------------------------------------------------------------------
// Single-pass lookback scan (79 blocks — proven regime).
__global__ __launch_bounds__(256) void k_scanf(const int* __restrict__ deg,
                                               int* __restrict__ offs,
                                               int* __restrict__ cursor,
                                               float* __restrict__ recip,
                                               int* __restrict__ bflag) {
    __shared__ int wsum[4];
    __shared__ int s_pre;
    const int tid = threadIdx.x, lane = tid & 63, wid = tid >> 6;
    const int bid = blockIdx.x;
    int i = bid * 256 + tid;
    int v = (i < NN) ? deg[i] : 0;
    int sc = v;
#pragma unroll
    for (int d = 1; d < 64; d <<= 1) {
        int t = __shfl_up(sc, d);
        if (lane >= d) sc += t;
    }
    if (lane == 63) wsum[wid] = sc;
    __syncthreads();
    int wpre = 0;
    for (int w = 0; w < wid; ++w) wpre += wsum[w];
    int btot = wsum[0] + wsum[1] + wsum[2] + wsum[3];

    if (tid == 0) atomicExch(&bflag[bid], btot + 1);

    int myv = 0;
    if (tid < bid) {
        int f;
        do { f = atomicAdd(&bflag[tid], 0); } while (f == 0);
        myv = f - 1;
    }
    int rs = myv;
#pragma unroll
    for (int d = 1; d < 64; d <<= 1) rs += __shfl_xor(rs, d);
    __syncthreads();
    if (lane == 0) wsum[wid] = rs;
    __syncthreads();
    if (tid == 0) s_pre = wsum[0] + wsum[1] + wsum[2] + wsum[3];
    __syncthreads();
    int pre = s_pre;

    if (i < NN) {
        int o = pre + wpre + sc - v;
        offs[i] = o;
        cursor[i] = o;
        recip[i] = 1.0f / fmaxf((float)v, 1.0f);
    }
    if (i == 0) offs[NN] = NE;
}

// Fill CSR adjacency: scol[cursor[row[e]]++] = col[e]  (1 edge/thread)
__global__ __launch_bounds__(256) void k_fill(const int* __restrict__ row,
                                              const int* __restrict__ col,
                                              int* __restrict__ cursor,
                                              int* __restrict__ scol) {
    int e = blockIdx.x * 256 + threadIdx.x;
    if (e < NE) {
        int r = row[e];
        int p = atomicAdd(&cursor[r], 1);
        scol[p] = col[e];
    }
}

// ---------------------------------------------------------------------------
// Gather + epilogue: out[i] = [relu]( recip[i]*sum_{c in N(i)} P[c,:]
//                                     + Q[i,:] + b )   (bf16 out)
template <int RELU>
__global__ __launch_bounds__(256) void k_gath(const int* __restrict__ offs,
                                              const int* __restrict__ scol,
                                              const float* __restrict__ recip,
                                              const unsigned short* __restrict__ P,
                                              const unsigned short* __restrict__ Q,
                                              const float* __restrict__ b,
                                              unsigned short* __restrict__ out) {
    int node = blockIdx.x * 4 + (threadIdx.x >> 6);
    int lane = threadIdx.x & 63;
    if (node >= NN) return;
    const int half = lane >> 5;
    const int l32 = lane & 31;

    // Hoisted epilogue loads (independent of gather loop).
    float rc = recip[node];
    u16x8 qv = *reinterpret_cast<const u16x8*>(Q + (size_t)node * DD + l32 * 8);
    float4 b0 = *reinterpret_cast<const float4*>(b + l32 * 8);
    float4 b1 = *reinterpret_cast<const float4*>(b + l32 * 8 + 4);

    int s = offs[node];
    int e = offs[node + 1];
    float a0[8] = {0,0,0,0,0,0,0,0}, a1[8] = {0,0,0,0,0,0,0,0};
    float a2[8] = {0,0,0,0,0,0,0,0}, a3[8] = {0,0,0,0,0,0,0,0};
    int p = s;
    for (; p + 7 < e; p += 8) {
        int base = p + 4 * half;
        int c0 = scol[base], c1 = scol[base + 1], c2 = scol[base + 2], c3 = scol[base + 3];
        u16x8 v0 = *reinterpret_cast<const u16x8*>(P + (size_t)c0 * DD + l32 * 8);
        u16x8 v1 = *reinterpret_cast<const u16x8*>(P + (size_t)c1 * DD + l32 * 8);
        u16x8 v2 = *reinterpret_cast<const u16x8*>(P + (size_t)c2 * DD + l32 * 8);
        u16x8 v3 = *reinterpret_cast<const u16x8*>(P + (size_t)c3 * DD + l32 * 8);
#pragma unroll
        for (int i = 0; i < 8; ++i) {
            a0[i] += bf2f(v0[i]); a1[i] += bf2f(v1[i]);
            a2[i] += bf2f(v2[i]); a3[i] += bf2f(v3[i]);
        }
    }
    for (; p + 1 < e; p += 2) {
        int c0 = scol[p + half];
        u16x8 v0 = *reinterpret_cast<const u16x8*>(P + (size_t)c0 * DD + l32 * 8);
#pragma unroll
        for (int i = 0; i < 8; ++i) a0[i] += bf2f(v0[i]);
    }
    if (p < e && half == 0) {
        int c0 = scol[p];
        u16x8 v0 = *reinterpret_cast<const u16x8*>(P + (size_t)c0 * DD + l32 * 8);
#pragma unroll
        for (int i = 0; i < 8; ++i) a1[i] += bf2f(v0[i]);
    }
    float bb[8] = {b0.x, b0.y, b0.z, b0.w, b1.x, b1.y, b1.z, b1.w};
    u16x8 o;
#pragma unroll
    for (int i = 0; i < 8; ++i) {
        float t = a0[i] + a1[i] + a2[i] + a3[i];
        t += __shfl_xor(t, 32);
        t = t * rc + bf2f(qv[i]) + bb[i];
        if (RELU) t = fmaxf(t, 0.0f);
        o[i] = f2bf(t);
    }
    if (half == 0)
        *reinterpret_cast<u16x8*>(out + (size_t)node * DD + l32 * 8) = o;
}

// ---------------------------------------------------------------------------
// Predictor: 512 threads = 8 waves, 128 queries/block.
// Edge indices hoisted; swizzled LDS; 4x4 retile; setprio around MFMA.
__global__ __launch_bounds__(512, 4) void k_pred(const int* __restrict__ edges,
                                                 const unsigned short* __restrict__ x2,
                                                 const unsigned short* __restrict__ Wp1p,
                                                 const float* __restrict__ bp1,
                                                 const float* __restrict__ Wp2,
                                                 const float* __restrict__ bp2,
                                                 float* __restrict__ out) {
    __shared__ unsigned short sh[128 * 256];   // 64KB bf16 h tile, swizzled
    const int tid = threadIdx.x;
    const int wave = tid >> 6;
    const int lane = tid & 63;
    const int q0 = blockIdx.x * 128;

    const int grow = tid >> 4;         // 0..31
    const int t16 = tid & 15;

    int ea[4], ec[4];
#pragma unroll
    for (int s = 0; s < 4; ++s) {
        int q = q0 + s * 32 + grow;
        bool ok = (q < NQ);
        ea[s] = ok ? edges[q] : 0;
        ec[s] = ok ? edges[NQ + q] : 0;
    }
#pragma unroll
    for (int s = 0; s < 4; ++s) {
        int r = s * 32 + grow;
        int q = q0 + r;
        u16x8 p0 = {0, 0, 0, 0, 0, 0, 0, 0};
        u16x8 p1 = {0, 0, 0, 0, 0, 0, 0, 0};
        if (q < NQ) {
            const unsigned short* pa = x2 + (size_t)ea[s] * DD + t16 * 16;
            const unsigned short* pc = x2 + (size_t)ec[s] * DD + t16 * 16;
            u16x8 ua0 = *reinterpret_cast<const u16x8*>(pa);
            u16x8 ua1 = *reinterpret_cast<const u16x8*>(pa + 8);
            u16x8 uc0 = *reinterpret_cast<const u16x8*>(pc);
            u16x8 uc1 = *reinterpret_cast<const u16x8*>(pc + 8);
#pragma unroll
            for (int i = 0; i < 8; ++i) {
                p0[i] = f2bf(bf2f(ua0[i]) * bf2f(uc0[i]));
                p1[i] = f2bf(bf2f(ua1[i]) * bf2f(uc1[i]));
            }
        }
        int swz = (r & 7) << 3;
        *reinterpret_cast<u16x8*>(&sh[r * 256 + ((t16 * 16) ^ swz)]) = p0;
        *reinterpret_cast<u16x8*>(&sh[r * 256 + ((t16 * 16 + 8) ^ swz)]) = p1;
    }
    __syncthreads();

    const int mg = wave >> 2;          // 0..1: row half
    const int ng = wave & 3;           // 0..3: nt quad
    f32x4 acc[4][4];                   // [m][n]
#pragma unroll
    for (int m = 0; m < 4; ++m)
#pragma unroll
        for (int n = 0; n < 4; ++n) acc[m][n] = {0, 0, 0, 0};

    const int akoff = (lane >> 4) * 8;
    const int arl = lane & 15;
    for (int kt = 0; kt < 8; ++kt) {
        bf16x8 af[4];
#pragma unroll
        for (int m = 0; m < 4; ++m) {
            int row = (mg * 4 + m) * 16 + arl;
            af[m] = *reinterpret_cast<const bf16x8*>(
                &sh[row * 256 + ((kt * 32 + akoff) ^ ((row & 7) << 3))]);
        }
#pragma unroll
        for (int n = 0; n < 4; ++n) {
            int nt = ng * 4 + n;
            bf16x8 bfrag = *reinterpret_cast<const bf16x8*>(
                Wp1p + ((size_t)((kt * 16 + nt) * 64 + lane)) * 8);
            __builtin_amdgcn_s_setprio(1);
#pragma unroll
            for (int m = 0; m < 4; ++m)
                acc[m][n] = __builtin_amdgcn_mfma_f32_16x16x32_bf16(af[m], bfrag, acc[m][n], 0, 0, 0);
            __builtin_amdgcn_s_setprio(0);
        }
    }

    // Epilogue: bias+relu+Wp2 partial dot within wave's 64 cols.
    float rs[4][4];   // [m][j]
#pragma unroll
    for (int m = 0; m < 4; ++m)
#pragma unroll
        for (int j = 0; j < 4; ++j) rs[m][j] = 0.0f;
#pragma unroll
    for (int n = 0; n < 4; ++n) {
        int nc = (ng * 4 + n) * 16 + (lane & 15);
        float bias = bp1[nc];
        float w2 = Wp2[nc];
#pragma unroll
        for (int m = 0; m < 4; ++m)
#pragma unroll
            for (int j = 0; j < 4; ++j)
                rs[m][j] += fmaxf(acc[m][n][j] + bias, 0.0f) * w2;
    }
#pragma unroll
    for (int msk = 1; msk < 16; msk <<= 1) {
#pragma unroll
        for (int m = 0; m < 4; ++m)
#pragma unroll
            for (int j = 0; j < 4; ++j) rs[m][j] += __shfl_xor(rs[m][j], msk);
    }

    float* psum = reinterpret_cast<float*>(sh);   // [4][128], aliases sh
    __syncthreads();
    if ((lane & 15) == 0) {
        int rg = (lane >> 4) * 4;
#pragma unroll
        for (int m = 0; m < 4; ++m)
#pragma unroll
            for (int j = 0; j < 4; ++j)
                psum[ng * 128 + (mg * 4 + m) * 16 + rg + j] = rs[m][j];
    }
    __syncthreads();

    if (tid < 128) {
        int q = q0 + tid;
        if (q < NQ) {
            float z = bp2[0];
#pragma unroll
            for (int w = 0; w < 4; ++w) z += psum[w * 128 + tid];
            out[q] = 1.0f / (1.0f + expf(-z));
        }
    }
}

// ---------------------------------------------------------------------------
extern "C" void kernel_launch(void* const* d_in, const int* in_sizes, int n_in,
                              void* d_out, int out_size, void* d_ws, size_t ws_size,
                              hipStream_t stream) {
    const int*   adj_row = (const int*)d_in[0];
    const int*   adj_col = (const int*)d_in[1];
    const int*   edges   = (const int*)d_in[2];
    const float* emb     = (const float*)d_in[3];
    const float* W1l     = (const float*)d_in[4];
    const float* b1      = (const float*)d_in[5];
    const float* W1r     = (const float*)d_in[6];
    const float* W2l     = (const float*)d_in[7];
    const float* b2      = (const float*)d_in[8];
    const float* W2r     = (const float*)d_in[9];
    const float* Wp1     = (const float*)d_in[10];
    const float* bp1     = (const float*)d_in[11];
    const float* Wp2     = (const float*)d_in[12];
    const float* bp2     = (const float*)d_in[13];
    float* out = (float*)d_out;

    const size_t featH = (size_t)NN * DD * 2;   // 10.24 MB
    const size_t packBytes = (size_t)DD * DD * 2;

    char* ws = (char*)d_ws;
    size_t off = 0;
    unsigned short* P  = (unsigned short*)(ws + off); off += featH;
    unsigned short* Q  = (unsigned short*)(ws + off); off += featH;
    unsigned short* x1 = (unsigned short*)(ws + off); off += featH;
    unsigned short* xh = (unsigned short*)(ws + off); off += featH;  // emb_bf16, later x2
    int*   deg    = (int*)(ws + off);   off += (size_t)NN * 4;
    int*   offs   = (int*)(ws + off);   off += (size_t)(NN + 1) * 4;
    int*   cursor = (int*)(ws + off);   off += (size_t)NN * 4;
    float* recip  = (float*)(ws + off); off += (size_t)NN * 4;
    int*   bflag  = (int*)(ws + off);   off += (size_t)NB * 4;
    int*   scol   = (int*)(ws + off);   off += (size_t)NE * 4;
    unsigned short* Wp1p = (unsigned short*)(ws + off); off += packBytes;
    unsigned short* pk[4];   // W1l,W1r,W2l,W2r (hi only)
    for (int i = 0; i < 4; ++i) { pk[i] = (unsigned short*)(ws + off); off += packBytes; }

    const int MB8 = ((NN + 63) / 64) * 8;   // 313 M-blocks x 8 N-eighths = 2504

    // 1. Fused cast + deg/flag zero + weight packs (hi only).
    k_castpack<<<CASTB + 160, 256, 0, stream>>>(emb, xh, deg, bflag,
                                                W1l, W1r, W2l, W2r, Wp1,
                                                pk[0], pk[1], pk[2], pk[3], Wp1p);
    // 2. Fused deg histogram + layer-1 GEMM (2x waves vs R17).
    k_deglin<<<DEGB + MB8, 256, 0, stream>>>(adj_row, deg, xh,
                                             pk[0], pk[1], P, Q);
    // 3. Lookback scan (79 blocks).
    k_scanf<<<NB, 256, 0, stream>>>(deg, offs, cursor, recip, bflag);
    // 4. CSR fill (1250 blocks, 1 edge/thread — fully parallel).
    k_fill<<<DEGB, 256, 0, stream>>>(adj_row, adj_col, cursor, scol);
    // 5. Layer 1 epilogue: x1 = relu(mean_N(P) + Q + b1)
    k_gath<1><<<(NN + 3) / 4, 256, 0, stream>>>(offs, scol, recip, P, Q, b1, x1);
    // 6. Layer 2 GEMM: P = x1@W2l, Q = x1@W2r
    k_lin<<<MB8, 256, 0, stream>>>(x1, pk[2], pk[3], P, Q);
    // 7. Layer 2 epilogue: x2 = mean_N(P) + Q + b2 (reuses xh)
    unsigned short* x2 = xh;   // emb_bf16 dead after k_deglin
    k_gath<0><<<(NN + 3) / 4, 256, 0, stream>>>(offs, scol, recip, P, Q, b2, x2);
    // 8. Predictor
    k_pred<<<(NQ + 127) / 128, 512, 0, stream>>>(edges, x2, Wp1p, bp1, Wp2, bp2, out);
}

// Round 19
// 182.470 us; speedup vs baseline: 1.0400x; 1.0400x over previous
//
#include <hip/hip_runtime.h>
#include <cstddef>

// Problem constants (match reference)
constexpr int NN = 20000;    // nodes
constexpr int NE = 320000;   // edges
constexpr int NQ = 100000;   // queries
constexpr int DD = 256;      // feature dim
constexpr int NB = (NN + 255) / 256;       // scan blocks (79)
constexpr int DEGB = (NE + 255) / 256;     // deg/fill blocks (1250)
constexpr int CASTB = (NN * DD / 8 + 255) / 256;   // 2500 cast blocks

typedef __attribute__((ext_vector_type(8))) short bf16x8;
typedef __attribute__((ext_vector_type(4))) float f32x4;
typedef __attribute__((ext_vector_type(4))) unsigned short u16x4;
typedef __attribute__((ext_vector_type(8))) unsigned short u16x8;

__device__ inline unsigned short f2bf(float f) {
    union { float f; unsigned u; } v; v.f = f;
    unsigned r = v.u + 0x7fffu + ((v.u >> 16) & 1u);   // RNE
    return (unsigned short)(r >> 16);
}
__device__ inline float bf2f(unsigned short h) {
    union { unsigned u; float f; } t; t.u = ((unsigned)h) << 16;
    return t.f;
}

// ---------------------------------------------------------------------------
// Fused: blocks [0,CASTB): emb f32->bf16 + deg zero (+ block 0: bflag zero).
//        blocks [CASTB, CASTB+160): pack 5 weight matrices into bf16 MFMA
//        B-fragment layout, HI ONLY (absmax 0.0078 vs threshold 0.0176).
__global__ __launch_bounds__(256) void k_castpack(
    const float* __restrict__ x, unsigned short* __restrict__ y,
    int* __restrict__ deg, int* __restrict__ bflag,
    const float* __restrict__ w0, const float* __restrict__ w1,
    const float* __restrict__ w2, const float* __restrict__ w3,
    const float* __restrict__ w4,
    unsigned short* __restrict__ h0, unsigned short* __restrict__ h1,
    unsigned short* __restrict__ h2, unsigned short* __restrict__ h3,
    unsigned short* __restrict__ h4) {
    const int bid = blockIdx.x;
    if (bid < CASTB) {
        int i = bid * 256 + threadIdx.x;   // 8 elems per thread
        if (i < NN) deg[i] = 0;
        if (bid == 0 && threadIdx.x < NB) bflag[threadIdx.x] = 0;
        if (i >= NN * DD / 8) return;
        float4 f0 = *reinterpret_cast<const float4*>(x + (size_t)i * 8);
        float4 f1 = *reinterpret_cast<const float4*>(x + (size_t)i * 8 + 4);
        u16x8 o;
        o[0] = f2bf(f0.x); o[1] = f2bf(f0.y); o[2] = f2bf(f0.z); o[3] = f2bf(f0.w);
        o[4] = f2bf(f1.x); o[5] = f2bf(f1.y); o[6] = f2bf(f1.z); o[7] = f2bf(f1.w);
        *reinterpret_cast<u16x8*>(y + (size_t)i * 8) = o;
        return;
    }
    int mb = bid - CASTB;                   // 0..159
    int m = mb >> 5;
    int idx = (mb & 31) * 256 + threadIdx.x;   // 0..8191
    const float* W = (m == 0) ? w0 : (m == 1) ? w1 : (m == 2) ? w2 : (m == 3) ? w3 : w4;
    unsigned short* H = (m == 0) ? h0 : (m == 1) ? h1 : (m == 2) ? h2 : (m == 3) ? h3 : h4;
    int t = idx >> 6, lane = idx & 63;
    int kt = t >> 4, nt = t & 15;
    int k0 = kt * 32 + (lane >> 4) * 8;
    int n = nt * 16 + (lane & 15);
    unsigned uh[4];
#pragma unroll
    for (int i = 0; i < 4; ++i) {
        unsigned lo = f2bf(W[(size_t)(k0 + 2 * i) * DD + n]);
        unsigned hi = f2bf(W[(size_t)(k0 + 2 * i + 1) * DD + n]);
        uh[i] = lo | (hi << 16);
    }
    *reinterpret_cast<uint4*>(H + (size_t)idx * 8) = make_uint4(uh[0], uh[1], uh[2], uh[3]);
}

// ---------------------------------------------------------------------------
// Dense dual GEMM body: P = A @ Wl, Q = A @ Wr (all bf16, hi-only weights).
// Wave = TWO 16-row M-tiles (32 rows) x 32 cols (N-eighth) — R17 optimum:
// R15 (half work) neutral, R18 (1 M-tile, 2x waves) regressed. Block = 4 waves.
__device__ __forceinline__ void lin_body(
    int bidx,
    const unsigned short* __restrict__ A,
    const unsigned short* __restrict__ Wl, const unsigned short* __restrict__ Wr,
    unsigned short* __restrict__ P, unsigned short* __restrict__ Q) {
    const int ns   = bidx & 7;
    const int mblk = bidx >> 3;
    const int wave = threadIdx.x >> 6;
    const int lane = threadIdx.x & 63;
    const int row0 = mblk * 128 + wave * 32;
    const int kcol = (lane >> 4) * 8;
    const int ar0 = min(row0 + (lane & 15), NN - 1);
    const int ar1 = min(row0 + 16 + (lane & 15), NN - 1);

    f32x4 accP[2][2], accQ[2][2];
#pragma unroll
    for (int mt = 0; mt < 2; ++mt)
#pragma unroll
        for (int nt = 0; nt < 2; ++nt) {
            accP[mt][nt] = {0, 0, 0, 0};
            accQ[mt][nt] = {0, 0, 0, 0};
        }

#pragma unroll 2
    for (int kt = 0; kt < 8; ++kt) {
        bf16x8 a0 = *reinterpret_cast<const bf16x8*>(A + (size_t)ar0 * DD + kt * 32 + kcol);
        bf16x8 a1 = *reinterpret_cast<const bf16x8*>(A + (size_t)ar1 * DD + kt * 32 + kcol);
#pragma unroll
        for (int nt = 0; nt < 2; ++nt) {
            const size_t fo = ((size_t)((kt * 16 + ns * 2 + nt) * 64 + lane)) * 8;
            bf16x8 bl = *reinterpret_cast<const bf16x8*>(Wl + fo);
            bf16x8 br = *reinterpret_cast<const bf16x8*>(Wr + fo);
            __builtin_amdgcn_s_setprio(1);
            accP[0][nt] = __builtin_amdgcn_mfma_f32_16x16x32_bf16(a0, bl, accP[0][nt], 0, 0, 0);
            accP[1][nt] = __builtin_amdgcn_mfma_f32_16x16x32_bf16(a1, bl, accP[1][nt], 0, 0, 0);
            accQ[0][nt] = __builtin_amdgcn_mfma_f32_16x16x32_bf16(a0, br, accQ[0][nt], 0, 0, 0);
            accQ[1][nt] = __builtin_amdgcn_mfma_f32_16x16x32_bf16(a1, br, accQ[1][nt], 0, 0, 0);
            __builtin_amdgcn_s_setprio(0);
        }
    }

    const int n0 = lane & 15;
    const int rg = (lane >> 4) * 4;
#pragma unroll
    for (int mt = 0; mt < 2; ++mt)
#pragma unroll
        for (int nt = 0; nt < 2; ++nt) {
            int n = (ns * 2 + nt) * 16 + n0;
#pragma unroll
            for (int j = 0; j < 4; ++j) {
                int r = row0 + mt * 16 + rg + j;
                if (r < NN) {
                    P[(size_t)r * DD + n] = f2bf(accP[mt][nt][j]);
                    Q[(size_t)r * DD + n] = f2bf(accQ[mt][nt][j]);
                }
            }
        }
}

// Layer-2 standalone GEMM.
__global__ __launch_bounds__(256) void k_lin(
    const unsigned short* __restrict__ A,
    const unsigned short* __restrict__ Wl, const unsigned short* __restrict__ Wr,
    unsigned short* __restrict__ P, unsigned short* __restrict__ Q) {
    lin_body(blockIdx.x, A, Wl, Wr, P, Q);
}

// Fused: blocks [0,DEGB) = degree histogram; rest = layer-1 GEMM.
__global__ __launch_bounds__(256) void k_deglin(
    const int* __restrict__ row, int* __restrict__ deg,
    const unsigned short* __restrict__ A,
    const unsigned short* __restrict__ Wl, const unsigned short* __restrict__ Wr,
    unsigned short* __restrict__ P, unsigned short* __restrict__ Q) {
    if (blockIdx.x < DEGB) {
        int e = blockIdx.x * 256 + threadIdx.x;
        if (e < NE) atomicAdd(&deg[row[e]], 1);
        return;
    }
    lin_body(blockIdx.x - DEGB, A, Wl, Wr, P, Q);
}

// ---------------------------------------------------------------------------
// Single-pass lookback scan (79 blocks — proven regime).
__global__ __launch_bounds__(256) void k_scanf(const int* __restrict__ deg,
                                               int* __restrict__ offs,
                                               int* __restrict__ cursor,
                                               float* __restrict__ recip,
                                               int* __restrict__ bflag) {
    __shared__ int wsum[4];
    __shared__ int s_pre;
    const int tid = threadIdx.x, lane = tid & 63, wid = tid >> 6;
    const int bid = blockIdx.x;
    int i = bid * 256 + tid;
    int v = (i < NN) ? deg[i] : 0;
    int sc = v;
#pragma unroll
    for (int d = 1; d < 64; d <<= 1) {
        int t = __shfl_up(sc, d);
        if (lane >= d) sc += t;
    }
    if (lane == 63) wsum[wid] = sc;
    __syncthreads();
    int wpre = 0;
    for (int w = 0; w < wid; ++w) wpre += wsum[w];
    int btot = wsum[0] + wsum[1] + wsum[2] + wsum[3];

    if (tid == 0) atomicExch(&bflag[bid], btot + 1);

    int myv = 0;
    if (tid < bid) {
        int f;
        do { f = atomicAdd(&bflag[tid], 0); } while (f == 0);
        myv = f - 1;
    }
    int rs = myv;
#pragma unroll
    for (int d = 1; d < 64; d <<= 1) rs += __shfl_xor(rs, d);
    __syncthreads();
    if (lane == 0) wsum[wid] = rs;
    __syncthreads();
    if (tid == 0) s_pre = wsum[0] + wsum[1] + wsum[2] + wsum[3];
    __syncthreads();
    int pre = s_pre;

    if (i < NN) {
        int o = pre + wpre + sc - v;
        offs[i] = o;
        cursor[i] = o;
        recip[i] = 1.0f / fmaxf((float)v, 1.0f);
    }
    if (i == 0) offs[NN] = NE;
}

// Fill CSR adjacency: scol[cursor[row[e]]++] = col[e]  (1 edge/thread)
__global__ __launch_bounds__(256) void k_fill(const int* __restrict__ row,
                                              const int* __restrict__ col,
                                              int* __restrict__ cursor,
                                              int* __restrict__ scol) {
    int e = blockIdx.x * 256 + threadIdx.x;
    if (e < NE) {
        int r = row[e];
        int p = atomicAdd(&cursor[r], 1);
        scol[p] = col[e];
    }
}

// ---------------------------------------------------------------------------
// Gather + epilogue: out[i] = [relu]( recip[i]*sum_{c in N(i)} P[c,:]
//                                     + Q[i,:] + b )   (bf16 out)
template <int RELU>
__global__ __launch_bounds__(256) void k_gath(const int* __restrict__ offs,
                                              const int* __restrict__ scol,
                                              const float* __restrict__ recip,
                                              const unsigned short* __restrict__ P,
                                              const unsigned short* __restrict__ Q,
                                              const float* __restrict__ b,
                                              unsigned short* __restrict__ out) {
    int node = blockIdx.x * 4 + (threadIdx.x >> 6);
    int lane = threadIdx.x & 63;
    if (node >= NN) return;
    const int half = lane >> 5;
    const int l32 = lane & 31;

    // Hoisted epilogue loads (independent of gather loop).
    float rc = recip[node];
    u16x8 qv = *reinterpret_cast<const u16x8*>(Q + (size_t)node * DD + l32 * 8);
    float4 b0 = *reinterpret_cast<const float4*>(b + l32 * 8);
    float4 b1 = *reinterpret_cast<const float4*>(b + l32 * 8 + 4);

    int s = offs[node];
    int e = offs[node + 1];
    float a0[8] = {0,0,0,0,0,0,0,0}, a1[8] = {0,0,0,0,0,0,0,0};
    float a2[8] = {0,0,0,0,0,0,0,0}, a3[8] = {0,0,0,0,0,0,0,0};
    int p = s;
    for (; p + 7 < e; p += 8) {
        int base = p + 4 * half;
        int c0 = scol[base], c1 = scol[base + 1], c2 = scol[base + 2], c3 = scol[base + 3];
        u16x8 v0 = *reinterpret_cast<const u16x8*>(P + (size_t)c0 * DD + l32 * 8);
        u16x8 v1 = *reinterpret_cast<const u16x8*>(P + (size_t)c1 * DD + l32 * 8);
        u16x8 v2 = *reinterpret_cast<const u16x8*>(P + (size_t)c2 * DD + l32 * 8);
        u16x8 v3 = *reinterpret_cast<const u16x8*>(P + (size_t)c3 * DD + l32 * 8);
#pragma unroll
        for (int i = 0; i < 8; ++i) {
            a0[i] += bf2f(v0[i]); a1[i] += bf2f(v1[i]);
            a2[i] += bf2f(v2[i]); a3[i] += bf2f(v3[i]);
        }
    }
    for (; p + 1 < e; p += 2) {
        int c0 = scol[p + half];
        u16x8 v0 = *reinterpret_cast<const u16x8*>(P + (size_t)c0 * DD + l32 * 8);
#pragma unroll
        for (int i = 0; i < 8; ++i) a0[i] += bf2f(v0[i]);
    }
    if (p < e && half == 0) {
        int c0 = scol[p];
        u16x8 v0 = *reinterpret_cast<const u16x8*>(P + (size_t)c0 * DD + l32 * 8);
#pragma unroll
        for (int i = 0; i < 8; ++i) a1[i] += bf2f(v0[i]);
    }
    float bb[8] = {b0.x, b0.y, b0.z, b0.w, b1.x, b1.y, b1.z, b1.w};
    u16x8 o;
#pragma unroll
    for (int i = 0; i < 8; ++i) {
        float t = a0[i] + a1[i] + a2[i] + a3[i];
        t += __shfl_xor(t, 32);
        t = t * rc + bf2f(qv[i]) + bb[i];
        if (RELU) t = fmaxf(t, 0.0f);
        o[i] = f2bf(t);
    }
    if (half == 0)
        *reinterpret_cast<u16x8*>(out + (size_t)node * DD + l32 * 8) = o;
}

// ---------------------------------------------------------------------------
// Predictor: 512 threads = 8 waves, 128 queries/block.
// Edge indices hoisted; swizzled LDS; 4x4 retile; setprio around MFMA.
__global__ __launch_bounds__(512, 4) void k_pred(const int* __restrict__ edges,
                                                 const unsigned short* __restrict__ x2,
                                                 const unsigned short* __restrict__ Wp1p,
                                                 const float* __restrict__ bp1,
                                                 const float* __restrict__ Wp2,
                                                 const float* __restrict__ bp2,
                                                 float* __restrict__ out) {
    __shared__ unsigned short sh[128 * 256];   // 64KB bf16 h tile, swizzled
    const int tid = threadIdx.x;
    const int wave = tid >> 6;
    const int lane = tid & 63;
    const int q0 = blockIdx.x * 128;

    const int grow = tid >> 4;         // 0..31
    const int t16 = tid & 15;

    int ea[4], ec[4];
#pragma unroll
    for (int s = 0; s < 4; ++s) {
        int q = q0 + s * 32 + grow;
        bool ok = (q < NQ);
        ea[s] = ok ? edges[q] : 0;
        ec[s] = ok ? edges[NQ + q] : 0;
    }
#pragma unroll
    for (int s = 0; s < 4; ++s) {
        int r = s * 32 + grow;
        int q = q0 + r;
        u16x8 p0 = {0, 0, 0, 0, 0, 0, 0, 0};
        u16x8 p1 = {0, 0, 0, 0, 0, 0, 0, 0};
        if (q < NQ) {
            const unsigned short* pa = x2 + (size_t)ea[s] * DD + t16 * 16;
            const unsigned short* pc = x2 + (size_t)ec[s] * DD + t16 * 16;
            u16x8 ua0 = *reinterpret_cast<const u16x8*>(pa);
            u16x8 ua1 = *reinterpret_cast<const u16x8*>(pa + 8);
            u16x8 uc0 = *reinterpret_cast<const u16x8*>(pc);
            u16x8 uc1 = *reinterpret_cast<const u16x8*>(pc + 8);
#pragma unroll
            for (int i = 0; i < 8; ++i) {
                p0[i] = f2bf(bf2f(ua0[i]) * bf2f(uc0[i]));
                p1[i] = f2bf(bf2f(ua1[i]) * bf2f(uc1[i]));
            }
        }
        int swz = (r & 7) << 3;
        *reinterpret_cast<u16x8*>(&sh[r * 256 + ((t16 * 16) ^ swz)]) = p0;
        *reinterpret_cast<u16x8*>(&sh[r * 256 + ((t16 * 16 + 8) ^ swz)]) = p1;
    }
    __syncthreads();

    const int mg = wave >> 2;          // 0..1: row half
    const int ng = wave & 3;           // 0..3: nt quad
    f32x4 acc[4][4];                   // [m][n]
#pragma unroll
    for (int m = 0; m < 4; ++m)
#pragma unroll
        for (int n = 0; n < 4; ++n) acc[m][n] = {0, 0, 0, 0};

    const int akoff = (lane >> 4) * 8;
    const int arl = lane & 15;
    for (int kt = 0; kt < 8; ++kt) {
        bf16x8 af[4];
#pragma unroll
        for (int m = 0; m < 4; ++m) {
            int row = (mg * 4 + m) * 16 + arl;
            af[m] = *reinterpret_cast<const bf16x8*>(
                &sh[row * 256 + ((kt * 32 + akoff) ^ ((row & 7) << 3))]);
        }
#pragma unroll
        for (int n = 0; n < 4; ++n) {
            int nt = ng * 4 + n;
            bf16x8 bfrag = *reinterpret_cast<const bf16x8*>(
                Wp1p + ((size_t)((kt * 16 + nt) * 64 + lane)) * 8);
            __builtin_amdgcn_s_setprio(1);
#pragma unroll
            for (int m = 0; m < 4; ++m)
                acc[m][n] = __builtin_amdgcn_mfma_f32_16x16x32_bf16(af[m], bfrag, acc[m][n], 0, 0, 0);
            __builtin_amdgcn_s_setprio(0);
        }
    }

    // Epilogue: bias+relu+Wp2 partial dot within wave's 64 cols.
    float rs[4][4];   // [m][j]
#pragma unroll
    for (int m = 0; m < 4; ++m)
#pragma unroll
        for (int j = 0; j < 4; ++j) rs[m][j] = 0.0f;
#pragma unroll
    for (int n = 0; n < 4; ++n) {
        int nc = (ng * 4 + n) * 16 + (lane & 15);
        float bias = bp1[nc];
        float w2 = Wp2[nc];
#pragma unroll
        for (int m = 0; m < 4; ++m)
#pragma unroll
            for (int j = 0; j < 4; ++j)
                rs[m][j] += fmaxf(acc[m][n][j] + bias, 0.0f) * w2;
    }
#pragma unroll
    for (int msk = 1; msk < 16; msk <<= 1) {
#pragma unroll
        for (int m = 0; m < 4; ++m)
#pragma unroll
            for (int j = 0; j < 4; ++j) rs[m][j] += __shfl_xor(rs[m][j], msk);
    }

    float* psum = reinterpret_cast<float*>(sh);   // [4][128], aliases sh
    __syncthreads();
    if ((lane & 15) == 0) {
        int rg = (lane >> 4) * 4;
#pragma unroll
        for (int m = 0; m < 4; ++m)
#pragma unroll
            for (int j = 0; j < 4; ++j)
                psum[ng * 128 + (mg * 4 + m) * 16 + rg + j] = rs[m][j];
    }
    __syncthreads();

    if (tid < 128) {
        int q = q0 + tid;
        if (q < NQ) {
            float z = bp2[0];
#pragma unroll
            for (int w = 0; w < 4; ++w) z += psum[w * 128 + tid];
            out[q] = 1.0f / (1.0f + expf(-z));
        }
    }
}

// ---------------------------------------------------------------------------
extern "C" void kernel_launch(void* const* d_in, const int* in_sizes, int n_in,
                              void* d_out, int out_size, void* d_ws, size_t ws_size,
                              hipStream_t stream) {
    const int*   adj_row = (const int*)d_in[0];
    const int*   adj_col = (const int*)d_in[1];
    const int*   edges   = (const int*)d_in[2];
    const float* emb     = (const float*)d_in[3];
    const float* W1l     = (const float*)d_in[4];
    const float* b1      = (const float*)d_in[5];
    const float* W1r     = (const float*)d_in[6];
    const float* W2l     = (const float*)d_in[7];
    const float* b2      = (const float*)d_in[8];
    const float* W2r     = (const float*)d_in[9];
    const float* Wp1     = (const float*)d_in[10];
    const float* bp1     = (const float*)d_in[11];
    const float* Wp2     = (const float*)d_in[12];
    const float* bp2     = (const float*)d_in[13];
    float* out = (float*)d_out;

    const size_t featH = (size_t)NN * DD * 2;   // 10.24 MB
    const size_t packBytes = (size_t)DD * DD * 2;

    char* ws = (char*)d_ws;
    size_t off = 0;
    unsigned short* P  = (unsigned short*)(ws + off); off += featH;
    unsigned short* Q  = (unsigned short*)(ws + off); off += featH;
    unsigned short* x1 = (unsigned short*)(ws + off); off += featH;
    unsigned short* xh = (unsigned short*)(ws + off); off += featH;  // emb_bf16, later x2
    int*   deg    = (int*)(ws + off);   off += (size_t)NN * 4;
    int*   offs   = (int*)(ws + off);   off += (size_t)(NN + 1) * 4;
    int*   cursor = (int*)(ws + off);   off += (size_t)NN * 4;
    float* recip  = (float*)(ws + off); off += (size_t)NN * 4;
    int*   bflag  = (int*)(ws + off);   off += (size_t)NB * 4;
    int*   scol   = (int*)(ws + off);   off += (size_t)NE * 4;
    unsigned short* Wp1p = (unsigned short*)(ws + off); off += packBytes;
    unsigned short* pk[4];   // W1l,W1r,W2l,W2r (hi only)
    for (int i = 0; i < 4; ++i) { pk[i] = (unsigned short*)(ws + off); off += packBytes; }

    const int MB8 = ((NN + 127) / 128) * 8;   // 157 M-blocks x 8 N-eighths

    // 1. Fused cast + deg/flag zero + weight packs (hi only).
    k_castpack<<<CASTB + 160, 256, 0, stream>>>(emb, xh, deg, bflag,
                                                W1l, W1r, W2l, W2r, Wp1,
                                                pk[0], pk[1], pk[2], pk[3], Wp1p);
    // 2. Fused deg histogram + layer-1 GEMM.
    k_deglin<<<DEGB + MB8, 256, 0, stream>>>(adj_row, deg, xh,
                                             pk[0], pk[1], P, Q);
    // 3. Lookback scan (79 blocks).
    k_scanf<<<NB, 256, 0, stream>>>(deg, offs, cursor, recip, bflag);
    // 4. CSR fill (1250 blocks, 1 edge/thread — fully parallel).
    k_fill<<<DEGB, 256, 0, stream>>>(adj_row, adj_col, cursor, scol);
    // 5. Layer 1 epilogue: x1 = relu(mean_N(P) + Q + b1)
    k_gath<1><<<(NN + 3) / 4, 256, 0, stream>>>(offs, scol, recip, P, Q, b1, x1);
    // 6. Layer 2 GEMM: P = x1@W2l, Q = x1@W2r
    k_lin<<<MB8, 256, 0, stream>>>(x1, pk[2], pk[3], P, Q);
    // 7. Layer 2 epilogue: x2 = mean_N(P) + Q + b2 (reuses xh)
    unsigned short* x2 = xh;   // emb_bf16 dead after k_deglin
    k_gath<0><<<(NN + 3) / 4, 256, 0, stream>>>(offs, scol, recip, P, Q, b2, x2);
    // 8. Predictor
    k_pred<<<(NQ + 127) / 128, 512, 0, stream>>>(edges, x2, Wp1p, bp1, Wp2, bp2, out);
}